// Round 1
// baseline (2231.117 us; speedup 1.0000x reference)
//
#include <hip/hip_runtime.h>
#include <hip/hip_bf16.h>
#include <stdint.h>

typedef __attribute__((ext_vector_type(4))) float f32x4;
typedef __attribute__((ext_vector_type(8))) __bf16 bf16x8;
typedef __attribute__((ext_vector_type(8))) short short8;

#define BM 128
#define BN 128
#define BK 32

// ---------------- reductions ----------------
__global__ void k_abssum_partial(const float* __restrict__ w, long long n4,
                                 double* __restrict__ partials) {
  const long long stride = (long long)gridDim.x * blockDim.x;
  const float4* w4 = (const float4*)w;
  double s = 0.0;
  for (long long i = (long long)blockIdx.x * blockDim.x + threadIdx.x; i < n4; i += stride) {
    float4 v = w4[i];
    s += (double)fabsf(v.x) + (double)fabsf(v.y) + (double)fabsf(v.z) + (double)fabsf(v.w);
  }
#pragma unroll
  for (int o = 32; o > 0; o >>= 1) s += __shfl_down(s, o);
  __shared__ double sm[4];
  if ((threadIdx.x & 63) == 0) sm[threadIdx.x >> 6] = s;
  __syncthreads();
  if (threadIdx.x == 0) partials[blockIdx.x] = (sm[0] + sm[1]) + (sm[2] + sm[3]);
}

__global__ void k_absmax(const float* __restrict__ x, long long n4,
                         unsigned* __restrict__ out) {
  const long long stride = (long long)gridDim.x * blockDim.x;
  const float4* x4 = (const float4*)x;
  float m = 0.0f;
  for (long long i = (long long)blockIdx.x * blockDim.x + threadIdx.x; i < n4; i += stride) {
    float4 v = x4[i];
    m = fmaxf(m, fmaxf(fmaxf(fabsf(v.x), fabsf(v.y)), fmaxf(fabsf(v.z), fabsf(v.w))));
  }
#pragma unroll
  for (int o = 32; o > 0; o >>= 1) m = fmaxf(m, __shfl_down(m, o));
  __shared__ float sm[4];
  if ((threadIdx.x & 63) == 0) sm[threadIdx.x >> 6] = m;
  __syncthreads();
  if (threadIdx.x == 0)
    atomicMax(out, __float_as_uint(fmaxf(fmaxf(sm[0], sm[1]), fmaxf(sm[2], sm[3]))));
}

__global__ void k_finalize(const double* __restrict__ partials, int np,
                           const unsigned* __restrict__ amax_bits,
                           long long nw, float* __restrict__ scal) {
  double s = 0.0;
  for (int i = threadIdx.x; i < np; i += 256) s += partials[i];
#pragma unroll
  for (int o = 32; o > 0; o >>= 1) s += __shfl_down(s, o);
  __shared__ double sm[4];
  if ((threadIdx.x & 63) == 0) sm[threadIdx.x >> 6] = s;
  __syncthreads();
  if (threadIdx.x == 0) {
    double tot = (sm[0] + sm[1]) + (sm[2] + sm[3]);
    float sf = fmaxf((float)(tot / (double)nw), 1e-5f);         // s = clip(mean|w|, EPS)
    float a = fmaxf(__uint_as_float(*amax_bits), 1e-5f);        // a = clip(max|x|, EPS)
    float act_scale = 127.0f / a;
    scal[0] = sf;
    scal[1] = act_scale;
    scal[2] = sf / act_scale;  // alpha for epilogue
  }
}

// ---------------- quantization (store exact small ints as bf16 bits) ----------------
__global__ void k_quant_w(const float* __restrict__ w, unsigned short* __restrict__ wq,
                          const float* __restrict__ scal, long long n8) {
  long long i = (long long)blockIdx.x * blockDim.x + threadIdx.x;
  if (i >= n8) return;
  const float s = scal[0];
  const float4* w4 = (const float4*)w;
  float4 a = w4[2 * i], b = w4[2 * i + 1];
  float v[8] = {a.x, a.y, a.z, a.w, b.x, b.y, b.z, b.w};
  short8 o;
#pragma unroll
  for (int j = 0; j < 8; ++j) {
    // match jnp: round-half-even of true fp32 division, then clip to [-1,1]
    float q = fminf(fmaxf(rintf(v[j] / s), -1.0f), 1.0f);
    o[j] = (short)(__float_as_uint(q) >> 16);  // exact bf16 for {-1,0,1}
  }
  ((short8*)wq)[i] = o;
}

__global__ void k_quant_x(const float* __restrict__ x, unsigned short* __restrict__ xq,
                          const float* __restrict__ scal, long long n8) {
  long long i = (long long)blockIdx.x * blockDim.x + threadIdx.x;
  if (i >= n8) return;
  const float as_ = scal[1];
  const float4* x4 = (const float4*)x;
  float4 a = x4[2 * i], b = x4[2 * i + 1];
  float v[8] = {a.x, a.y, a.z, a.w, b.x, b.y, b.z, b.w};
  short8 o;
#pragma unroll
  for (int j = 0; j < 8; ++j) {
    float q = fminf(fmaxf(rintf(v[j] * as_), -128.0f), 127.0f);
    o[j] = (short)(__float_as_uint(q) >> 16);  // exact bf16 for ints in [-128,127]
  }
  ((short8*)xq)[i] = o;
}

// ---------------- GEMM: C[m][n] = alpha * sum_k A[m][k]*B[n][k] + bias[n] ----------------
// m97 structure: 128x128 tile, BK=32, 4 waves (2x2), global_load_lds width-16 staging,
// 16x16x32 bf16 MFMA, 2 barriers per K-step (compiler drains vmcnt at barrier).
__global__ __launch_bounds__(256) void k_gemm(
    const __bf16* __restrict__ A,   // [M][K] quantized activations (exact ints)
    const __bf16* __restrict__ B,   // [N][K] ternary weights
    const float* __restrict__ bias,
    const float* __restrict__ scal,
    float* __restrict__ C, int M, int N, int K) {
  __shared__ __attribute__((aligned(16))) __bf16 sA[BM * BK];  // 8 KB
  __shared__ __attribute__((aligned(16))) __bf16 sB[BN * BK];  // 8 KB

  const int tid = threadIdx.x;
  const int wid = tid >> 6;
  const int lane = tid & 63;

  // XCD-aware swizzle (nwg = 8192, divisible by 8)
  const int nwg = gridDim.x;
  const int b = blockIdx.x;
  int swz;
  if ((nwg & 7) == 0) {
    const int cpx = nwg >> 3;
    swz = (b & 7) * cpx + (b >> 3);
  } else {
    swz = b;
  }
  const int ntn = N / BN;
  const int tm = swz / ntn, tn = swz % ntn;

  const int wr = wid >> 1, wc = wid & 1;  // 2x2 wave grid, each wave: 64x64 out

  f32x4 acc[4][4];
#pragma unroll
  for (int i = 0; i < 4; ++i)
#pragma unroll
    for (int j = 0; j < 4; ++j) acc[i][j] = (f32x4){0.f, 0.f, 0.f, 0.f};

  // staging: tile = 512 chunks of 16B; chunk c -> row c>>2, k-offset (c&3)*8
  const __bf16* gA = A + (long long)tm * BM * K;
  const __bf16* gB = B + (long long)tn * BN * K;
  const int c0 = wid * 64 + lane;  // issue 0 chunk
  const int c1 = c0 + 256;         // issue 1 chunk
  const __bf16* pA0 = gA + (long long)(c0 >> 2) * K + (c0 & 3) * 8;
  const __bf16* pA1 = gA + (long long)(c1 >> 2) * K + (c1 & 3) * 8;
  const __bf16* pB0 = gB + (long long)(c0 >> 2) * K + (c0 & 3) * 8;
  const __bf16* pB1 = gB + (long long)(c1 >> 2) * K + (c1 & 3) * 8;

  char* lA = (char*)sA;
  char* lB = (char*)sB;
  const int d0 = (wid * 64) * 16;          // wave-uniform LDS byte base, issue 0
  const int d1 = (256 + wid * 64) * 16;    // issue 1

  const int frow = lane & 15;
  const int fgrp = lane >> 4;

  const int nt = K / BK;
  for (int t = 0; t < nt; ++t) {
    __builtin_amdgcn_global_load_lds(
        (const __attribute__((address_space(1))) void*)pA0,
        (__attribute__((address_space(3))) void*)(lA + d0), 16, 0, 0);
    __builtin_amdgcn_global_load_lds(
        (const __attribute__((address_space(1))) void*)pA1,
        (__attribute__((address_space(3))) void*)(lA + d1), 16, 0, 0);
    __builtin_amdgcn_global_load_lds(
        (const __attribute__((address_space(1))) void*)pB0,
        (__attribute__((address_space(3))) void*)(lB + d0), 16, 0, 0);
    __builtin_amdgcn_global_load_lds(
        (const __attribute__((address_space(1))) void*)pB1,
        (__attribute__((address_space(3))) void*)(lB + d1), 16, 0, 0);
    pA0 += BK; pA1 += BK; pB0 += BK; pB1 += BK;
    __syncthreads();  // compiler emits s_waitcnt vmcnt(0) before s_barrier -> LDS ready

    bf16x8 af[4], bg[4];
#pragma unroll
    for (int i = 0; i < 4; ++i) {
      af[i] = *(const bf16x8*)(sA + (wr * 64 + i * 16 + frow) * BK + fgrp * 8);
      bg[i] = *(const bf16x8*)(sB + (wc * 64 + i * 16 + frow) * BK + fgrp * 8);
    }
#pragma unroll
    for (int i = 0; i < 4; ++i)
#pragma unroll
      for (int j = 0; j < 4; ++j)
        acc[i][j] = __builtin_amdgcn_mfma_f32_16x16x32_bf16(af[i], bg[j], acc[i][j], 0, 0, 0);
    __syncthreads();  // protect sA/sB before next stage
  }

  // epilogue: C/D layout col=lane&15, row=(lane>>4)*4+reg (HW-verified)
  const float alpha = scal[2];
  const int colbase = tn * BN + wc * 64;
  float bv[4];
#pragma unroll
  for (int j = 0; j < 4; ++j) bv[j] = bias[colbase + j * 16 + frow];
  const long long cb = (long long)(tm * BM + wr * 64) * N + colbase;
#pragma unroll
  for (int i = 0; i < 4; ++i) {
#pragma unroll
    for (int j = 0; j < 4; ++j) {
#pragma unroll
      for (int r = 0; r < 4; ++r) {
        const int row = i * 16 + fgrp * 4 + r;
        C[cb + (long long)row * N + j * 16 + frow] = alpha * acc[i][j][r] + bv[j];
      }
    }
  }
}

// ---------------- launch ----------------
extern "C" void kernel_launch(void* const* d_in, const int* in_sizes, int n_in,
                              void* d_out, int out_size, void* d_ws, size_t ws_size,
                              hipStream_t stream) {
  const float* x = (const float*)d_in[0];
  const float* w = (const float*)d_in[1];
  const float* bias = (const float*)d_in[2];
  float* out = (float*)d_out;

  const long long nx = in_sizes[0];         // B*S*DIN = 33554432
  const long long nw = in_sizes[1];         // DOUT*DIN = 67108864
  const int DOUT = in_sizes[2];             // 16384
  const int DIN = (int)(nw / DOUT);         // 4096
  const int M = (int)(nx / DIN);            // 8192
  const int N = DOUT, K = DIN;

  char* ws = (char*)d_ws;
  // layout: [0..7] unused, [8..11] amax bits, [16..31] scal, [64..16447] partials,
  //         [32768..] xq (nx*2 B), then wq (nw*2 B)
  unsigned* d_amax = (unsigned*)(ws + 8);
  float* d_scal = (float*)(ws + 16);
  double* d_part = (double*)(ws + 64);
  unsigned short* xq = (unsigned short*)(ws + 32768);
  unsigned short* wq = (unsigned short*)(ws + 32768 + (size_t)nx * 2);

  hipMemsetAsync(d_ws, 0, 64, stream);

  const int RB = 2048;
  k_abssum_partial<<<RB, 256, 0, stream>>>(w, nw >> 2, d_part);
  k_absmax<<<RB, 256, 0, stream>>>(x, nx >> 2, d_amax);
  k_finalize<<<1, 256, 0, stream>>>(d_part, RB, d_amax, nw, d_scal);

  k_quant_w<<<(int)(nw / 8 / 256), 256, 0, stream>>>(w, wq, d_scal, nw / 8);
  k_quant_x<<<(int)(nx / 8 / 256), 256, 0, stream>>>(x, xq, d_scal, nx / 8);

  const int grid = (M / BM) * (N / BN);  // 64 * 128 = 8192
  k_gemm<<<grid, 256, 0, stream>>>((const __bf16*)xq, (const __bf16*)wq, bias, d_scal,
                                   out, M, N, K);
}

// Round 4
// 1777.508 us; speedup vs baseline: 1.2552x; 1.2552x over previous
//
#include <hip/hip_runtime.h>
#include <hip/hip_bf16.h>
#include <stdint.h>

typedef __attribute__((ext_vector_type(4))) float f32x4;
typedef __attribute__((ext_vector_type(8))) __bf16 bf16x8;
typedef __attribute__((ext_vector_type(8))) short short8;

// ---------------- reductions ----------------
__global__ void k_abssum_partial(const float* __restrict__ w, long long n4,
                                 double* __restrict__ partials) {
  const long long stride = (long long)gridDim.x * blockDim.x;
  const float4* w4 = (const float4*)w;
  double s = 0.0;
  for (long long i = (long long)blockIdx.x * blockDim.x + threadIdx.x; i < n4; i += stride) {
    float4 v = w4[i];
    s += (double)fabsf(v.x) + (double)fabsf(v.y) + (double)fabsf(v.z) + (double)fabsf(v.w);
  }
#pragma unroll
  for (int o = 32; o > 0; o >>= 1) s += __shfl_down(s, o);
  __shared__ double sm[4];
  if ((threadIdx.x & 63) == 0) sm[threadIdx.x >> 6] = s;
  __syncthreads();
  if (threadIdx.x == 0) partials[blockIdx.x] = (sm[0] + sm[1]) + (sm[2] + sm[3]);
}

__global__ void k_absmax(const float* __restrict__ x, long long n4,
                         unsigned* __restrict__ out) {
  const long long stride = (long long)gridDim.x * blockDim.x;
  const float4* x4 = (const float4*)x;
  float m = 0.0f;
  for (long long i = (long long)blockIdx.x * blockDim.x + threadIdx.x; i < n4; i += stride) {
    float4 v = x4[i];
    m = fmaxf(m, fmaxf(fmaxf(fabsf(v.x), fabsf(v.y)), fmaxf(fabsf(v.z), fabsf(v.w))));
  }
#pragma unroll
  for (int o = 32; o > 0; o >>= 1) m = fmaxf(m, __shfl_down(m, o));
  __shared__ float sm[4];
  if ((threadIdx.x & 63) == 0) sm[threadIdx.x >> 6] = m;
  __syncthreads();
  if (threadIdx.x == 0)
    atomicMax(out, __float_as_uint(fmaxf(fmaxf(sm[0], sm[1]), fmaxf(sm[2], sm[3]))));
}

__global__ void k_finalize(const double* __restrict__ partials, int np,
                           const unsigned* __restrict__ amax_bits,
                           long long nw, float* __restrict__ scal) {
  double s = 0.0;
  for (int i = threadIdx.x; i < np; i += 256) s += partials[i];
#pragma unroll
  for (int o = 32; o > 0; o >>= 1) s += __shfl_down(s, o);
  __shared__ double sm[4];
  if ((threadIdx.x & 63) == 0) sm[threadIdx.x >> 6] = s;
  __syncthreads();
  if (threadIdx.x == 0) {
    double tot = (sm[0] + sm[1]) + (sm[2] + sm[3]);
    float sf = fmaxf((float)(tot / (double)nw), 1e-5f);         // s = clip(mean|w|, EPS)
    float a = fmaxf(__uint_as_float(*amax_bits), 1e-5f);        // a = clip(max|x|, EPS)
    float act_scale = 127.0f / a;
    scal[0] = sf;
    scal[1] = act_scale;
    scal[2] = sf / act_scale;  // alpha for epilogue
  }
}

// ---------------- quantization (store exact small ints as bf16 bits) ----------------
__global__ void k_quant_w(const float* __restrict__ w, unsigned short* __restrict__ wq,
                          const float* __restrict__ scal, long long n8) {
  long long i = (long long)blockIdx.x * blockDim.x + threadIdx.x;
  if (i >= n8) return;
  const float s = scal[0];
  const float4* w4 = (const float4*)w;
  float4 a = w4[2 * i], b = w4[2 * i + 1];
  float v[8] = {a.x, a.y, a.z, a.w, b.x, b.y, b.z, b.w};
  short8 o;
#pragma unroll
  for (int j = 0; j < 8; ++j) {
    float q = fminf(fmaxf(rintf(v[j] / s), -1.0f), 1.0f);
    o[j] = (short)(__float_as_uint(q) >> 16);  // exact bf16 for {-1,0,1}
  }
  ((short8*)wq)[i] = o;
}

__global__ void k_quant_x(const float* __restrict__ x, unsigned short* __restrict__ xq,
                          const float* __restrict__ scal, long long n8) {
  long long i = (long long)blockIdx.x * blockDim.x + threadIdx.x;
  if (i >= n8) return;
  const float as_ = scal[1];
  const float4* x4 = (const float4*)x;
  float4 a = x4[2 * i], b = x4[2 * i + 1];
  float v[8] = {a.x, a.y, a.z, a.w, b.x, b.y, b.z, b.w};
  short8 o;
#pragma unroll
  for (int j = 0; j < 8; ++j) {
    float q = fminf(fmaxf(rintf(v[j] * as_), -128.0f), 127.0f);
    o[j] = (short)(__float_as_uint(q) >> 16);  // exact bf16 for ints in [-128,127]
  }
  ((short8*)xq)[i] = o;
}

// ---------------- GEMM: 256x256 tile, BK=64, 8 waves, 8-phase counted-vmcnt schedule ----
// C[m][n] = alpha * sum_k A[m][k]*B[n][k] + bias[n]
// LDS per buf: [A-k0][B-k0][A-k1][B-k1], each half-tile 16KB (A: 256rows x 32k bf16).
// Stage stream: half s -> tile s>>2, h=s&3 (kh=h>>1, ab=h&1). At (tile t, phase p)
// issue s = 4t+p+5. One vmcnt(4) per tile (phase 4) guarantees tile t+1 resident.
// st_16x32 swizzle: linear LDS dest + pre-swizzled global chunk (c ^= ((c>>5)&1)<<1),
// read-side XOR folds to the per-thread constant ((frow&8)<<2).
__global__ __launch_bounds__(512, 2) void k_gemm(
    const __bf16* __restrict__ A,   // [M][K] quantized activations (exact ints)
    const __bf16* __restrict__ B,   // [N][K] ternary weights
    const float* __restrict__ bias,
    const float* __restrict__ scal,
    float* __restrict__ C, int M, int N, int K) {
  __shared__ __attribute__((aligned(128))) char Lds[131072];
  char* Lc = Lds;

  const int tid = threadIdx.x;
  const int wid = tid >> 6;
  const int lane = tid & 63;
  const int frow = lane & 15;
  const int fgrp = lane >> 4;
  const int wr = wid >> 2;   // 2 wave-rows: 128 out-rows each
  const int wc = wid & 3;    // 4 wave-cols: 64 out-cols each

  // XCD-aware chunked swizzle (nwg = 2048, divisible by 8)
  const int nwg = gridDim.x;
  const int b = blockIdx.x;
  int swz = b;
  if ((nwg & 7) == 0) swz = (b & 7) * (nwg >> 3) + (b >> 3);
  const int ntn = N >> 8;
  const int tm = swz / ntn, tn = swz % ntn;

  // staging source precompute: chunk c = tid, pre-swizzled c' (bit1 ^= bit5)
  const int cs = tid ^ (((tid >> 5) & 1) << 1);
  const int srow = cs >> 2;            // 0..127
  const int skp = (cs & 3) * 8;        // k-octet within 32-k half
  const size_t K128 = (size_t)128 * K;
  const __bf16* pA = A + (size_t)(tm * 256 + srow) * K + skp;
  const __bf16* pB = B + (size_t)(tn * 256 + srow) * K + skp;

  auto STAGE = [&](int s) {
    const int ts = s >> 2, h = s & 3;
    const int kh = h >> 1, ab = h & 1;
    char* dst = Lc + ((ts & 1) << 16) + (h << 14) + (wid << 10);
    const __bf16* src = (ab ? pB : pA) + ts * 64 + kh * 32;
    __builtin_amdgcn_global_load_lds(
        (const __attribute__((address_space(1))) void*)src,
        (__attribute__((address_space(3))) void*)dst, 16, 0, 0);
    __builtin_amdgcn_global_load_lds(
        (const __attribute__((address_space(1))) void*)(src + K128),
        (__attribute__((address_space(3))) void*)(dst + 8192), 16, 0, 0);
  };

  // fragment read bases (swizzle XOR is a per-thread constant)
  const int aoff = (((wr * 128 + frow) * 64) + fgrp * 16) ^ ((frow & 8) << 2);
  const int boff = (((wc * 64 + frow) * 64) + fgrp * 16) ^ ((frow & 8) << 2);

  bf16x8 av[4], bv_[4];
  f32x4 acc[8][4];
#pragma unroll
  for (int m = 0; m < 8; ++m)
#pragma unroll
    for (int n = 0; n < 4; ++n) acc[m][n] = (f32x4){0.f, 0.f, 0.f, 0.f};

  auto LDA = [&](int buf, int kh, int mh) {
    const char* p = Lc + buf * 65536 + kh * 32768 + aoff + mh * 4096;
#pragma unroll
    for (int m = 0; m < 4; ++m) av[m] = *(const bf16x8*)(p + m * 1024);
  };
  auto LDB = [&](int buf, int kh) {
    const char* p = Lc + buf * 65536 + kh * 32768 + 16384 + boff;
#pragma unroll
    for (int n = 0; n < 4; ++n) bv_[n] = *(const bf16x8*)(p + n * 1024);
  };
  auto MFMA = [&](int mh) {
    __builtin_amdgcn_s_setprio(1);
#pragma unroll
    for (int m = 0; m < 4; ++m)
#pragma unroll
      for (int n = 0; n < 4; ++n)
        acc[mh * 4 + m][n] =
            __builtin_amdgcn_mfma_f32_16x16x32_bf16(av[m], bv_[n], acc[mh * 4 + m][n], 0, 0, 0);
    __builtin_amdgcn_s_setprio(0);
  };
  auto BAR = [&] {
    asm volatile("" ::: "memory");
    __builtin_amdgcn_s_barrier();
    asm volatile("" ::: "memory");
  };

  // prologue: tile0 (h0..h3) + tile1 (h0,h1); wait tile0 complete (8 of 12 loads)
  STAGE(0); STAGE(1); STAGE(2); STAGE(3); STAGE(4); STAGE(5);
  asm volatile("s_waitcnt vmcnt(4)" ::: "memory");
  BAR();

  const int NPAIR = K >> 7;  // K/128 tile-pairs
  for (int tp = 0; tp < NPAIR - 1; ++tp) {
    const int s0 = (tp << 3) + 6;
    // tile 2tp (buf 0)
    LDA(0, 0, 0); LDB(0, 0); STAGE(s0 + 0); BAR(); MFMA(0); BAR();
    LDA(0, 0, 1);            STAGE(s0 + 1); BAR(); MFMA(1); BAR();
    LDA(0, 1, 0); LDB(0, 1); STAGE(s0 + 2); BAR(); MFMA(0); BAR();
    LDA(0, 1, 1);            STAGE(s0 + 3);
    asm volatile("s_waitcnt vmcnt(4)" ::: "memory");
    BAR(); MFMA(1); BAR();
    // tile 2tp+1 (buf 1)
    LDA(1, 0, 0); LDB(1, 0); STAGE(s0 + 4); BAR(); MFMA(0); BAR();
    LDA(1, 0, 1);            STAGE(s0 + 5); BAR(); MFMA(1); BAR();
    LDA(1, 1, 0); LDB(1, 1); STAGE(s0 + 6); BAR(); MFMA(0); BAR();
    LDA(1, 1, 1);            STAGE(s0 + 7);
    asm volatile("s_waitcnt vmcnt(4)" ::: "memory");
    BAR(); MFMA(1); BAR();
  }
  // epilogue pair: tiles 2*NPAIR-2 (buf0), 2*NPAIR-1 (buf1)
  {
    const int s0 = ((NPAIR - 1) << 3) + 6;  // last two valid halves: s0, s0+1
    LDA(0, 0, 0); LDB(0, 0); STAGE(s0 + 0); BAR(); MFMA(0); BAR();
    LDA(0, 0, 1);            STAGE(s0 + 1); BAR(); MFMA(1); BAR();
    LDA(0, 1, 0); LDB(0, 1);                BAR(); MFMA(0); BAR();
    LDA(0, 1, 1);
    asm volatile("s_waitcnt vmcnt(0)" ::: "memory");
    BAR(); MFMA(1); BAR();
    LDA(1, 0, 0); LDB(1, 0); BAR(); MFMA(0); BAR();
    LDA(1, 0, 1);            BAR(); MFMA(1); BAR();
    LDA(1, 1, 0); LDB(1, 1); BAR(); MFMA(0); BAR();
    LDA(1, 1, 1);            BAR(); MFMA(1);
  }

  // epilogue: C/D layout col=lane&15, row=(lane>>4)*4+reg (HW-verified, round-1 passed)
  const float alpha = scal[2];
  const int colbase = tn * 256 + wc * 64;
  float bb[4];
#pragma unroll
  for (int n = 0; n < 4; ++n) bb[n] = bias[colbase + n * 16 + frow];
  const long long cb = (long long)(tm * 256 + wr * 128) * N + colbase;
#pragma unroll
  for (int m = 0; m < 8; ++m) {
#pragma unroll
    for (int n = 0; n < 4; ++n) {
#pragma unroll
      for (int r = 0; r < 4; ++r) {
        const int row = m * 16 + fgrp * 4 + r;
        C[cb + (long long)row * N + n * 16 + frow] = alpha * acc[m][n][r] + bb[n];
      }
    }
  }
}

// ---------------- launch ----------------
extern "C" void kernel_launch(void* const* d_in, const int* in_sizes, int n_in,
                              void* d_out, int out_size, void* d_ws, size_t ws_size,
                              hipStream_t stream) {
  const float* x = (const float*)d_in[0];
  const float* w = (const float*)d_in[1];
  const float* bias = (const float*)d_in[2];
  float* out = (float*)d_out;

  const long long nx = in_sizes[0];         // B*S*DIN = 33554432
  const long long nw = in_sizes[1];         // DOUT*DIN = 67108864
  const int DOUT = in_sizes[2];             // 16384
  const int DIN = (int)(nw / DOUT);         // 4096
  const int M = (int)(nx / DIN);            // 8192
  const int N = DOUT, K = DIN;

  char* ws = (char*)d_ws;
  unsigned* d_amax = (unsigned*)(ws + 8);
  float* d_scal = (float*)(ws + 16);
  double* d_part = (double*)(ws + 64);
  unsigned short* xq = (unsigned short*)(ws + 32768);
  unsigned short* wq = (unsigned short*)(ws + 32768 + (size_t)nx * 2);

  hipMemsetAsync(d_ws, 0, 64, stream);

  const int RB = 2048;
  k_abssum_partial<<<RB, 256, 0, stream>>>(w, nw >> 2, d_part);
  k_absmax<<<RB, 256, 0, stream>>>(x, nx >> 2, d_amax);
  k_finalize<<<1, 256, 0, stream>>>(d_part, RB, d_amax, nw, d_scal);

  k_quant_w<<<(int)(nw / 8 / 256), 256, 0, stream>>>(w, wq, d_scal, nw / 8);
  k_quant_x<<<(int)(nx / 8 / 256), 256, 0, stream>>>(x, xq, d_scal, nx / 8);

  const int grid = (M / 256) * (N / 256);  // 32 * 64 = 2048
  k_gemm<<<grid, 512, 0, stream>>>((const __bf16*)xq, (const __bf16*)wq, bias, d_scal,
                                   out, M, N, K);
}